// Round 4
// baseline (441.156 us; speedup 1.0000x reference)
//
#include <hip/hip_runtime.h>

#define BATCH 65536
#define FEAT 1024
#define NCLS 96
#define NB 2048
#define NT 256
#define F4 (FEAT / 4)   // 256 float4 per feature row

typedef float vfloat4 __attribute__((ext_vector_type(4)));  // native vec for nontemporal builtin

// Row-per-block: block b handles rows {b, b+NB, ...} (32 rows), 256 threads x
// float4 covers exactly one 1024-float row per iteration.
//
// Memory config = Round-2 known-good (340.8 us): nt features loads, unroll 4
// (8 float4 in flight/thread -> latency-hiding for MALL-resident stream),
// NO min-blocks VGPR cap (R3's unroll2 + 64-VGPR cap regressed +17 us).
//
//  - `row` is scalar (blockIdx-derived only) -> labels[row] is an s_load and
//    the centers row base lives in SGPRs.
//  - per-thread element sequence is BIT-IDENTICAL to the 352.8us baseline
//    (row b+2048n, k4 = tid), so per-block partials match exactly.
//  - finalize FUSED: each block atomicAdds its double partial into ws.acc,
//    then takes a ticket; the last block writes out. Double accumulation ->
//    order-independent result under the final float cast (absmax 0.0).
//    ws[0:16) is zeroed by a 16-byte hipMemsetAsync each launch (workspace
//    is poisoned by the harness).
//
// clamp note: per-row distance is a sum of 1024 squares (magnitude ~2048);
// clip(d,1e-12,1e12) is a no-op on the true-label column. Masked-out entries
// clip to 1e-12 each -> constant (NCLS-1)*1e-12 added at finalize.
__global__ __launch_bounds__(NT) void center_loss_fused(
    const float* __restrict__ features,
    const float* __restrict__ centers,
    const int* __restrict__ labels,
    float* __restrict__ out,
    double* __restrict__ acc_ws,          // ws+0: double accumulator
    unsigned int* __restrict__ ticket_ws) // ws+8: block-completion counter
{
    const int tid = threadIdx.x;
    const vfloat4* __restrict__ f4 = (const vfloat4*)features;
    const float4*  __restrict__ c4 = (const float4*)centers;

    float acc = 0.f;
#pragma unroll 4
    for (int row = blockIdx.x; row < BATCH; row += NB) {
        const int lbl = labels[row];                        // block-uniform -> s_load
        const vfloat4 f = __builtin_nontemporal_load(&f4[(size_t)row * F4 + tid]);
        const float4 c = c4[(size_t)lbl * F4 + tid];
        const float dx = f.x - c.x, dy = f.y - c.y;
        const float dz = f.z - c.z, dw = f.w - c.w;
        acc += dx * dx + dy * dy + dz * dz + dw * dw;
    }

    // wave butterfly + tiny LDS block reduce (once per thread)
#pragma unroll
    for (int off = 32; off > 0; off >>= 1) acc += __shfl_xor(acc, off, 64);

    __shared__ float wave_sums[NT / 64];
    if ((tid & 63) == 0) wave_sums[tid >> 6] = acc;
    __syncthreads();
    if (tid == 0) {
        float s = 0.f;
#pragma unroll
        for (int w = 0; w < NT / 64; ++w) s += wave_sums[w];

        // device-scope accumulate + ticket; atomics bypass L1/L2 staleness
        atomicAdd(acc_ws, (double)s);
        __threadfence();
        const unsigned int old = atomicAdd(ticket_ws, 1u);
        if (old == NB - 1) {                      // last block finalizes
            const double total = atomicAdd(acc_ws, 0.0);   // coherent read
            const double masked = (double)(NCLS - 1) * 1e-12;
            out[0] = (float)(total / (double)BATCH + masked);
        }
    }
}

extern "C" void kernel_launch(void* const* d_in, const int* in_sizes, int n_in,
                              void* d_out, int out_size, void* d_ws, size_t ws_size,
                              hipStream_t stream) {
    const float* features = (const float*)d_in[0];
    const float* centers  = (const float*)d_in[1];
    const int*   labels   = (const int*)d_in[2];
    float* out = (float*)d_out;

    double* acc_ws = (double*)d_ws;
    unsigned int* ticket_ws = (unsigned int*)((char*)d_ws + 8);

    hipMemsetAsync(d_ws, 0, 16, stream);  // zero accumulator + ticket (ws is poisoned)
    center_loss_fused<<<NB, NT, 0, stream>>>(features, centers, labels, out,
                                             acc_ws, ticket_ws);
}

// Round 5
// 339.511 us; speedup vs baseline: 1.2994x; 1.2994x over previous
//
#include <hip/hip_runtime.h>

#define BATCH 65536
#define FEAT 1024
#define NCLS 96
#define NB 2048
#define NT 256
#define F4 (FEAT / 4)   // 256 float4 per feature row

typedef float vfloat4 __attribute__((ext_vector_type(4)));  // native vec for nontemporal builtin

// Round-2 known-good configuration (340.8 us) — exact revert.
//
// Row-per-block: block b handles rows {b, b+NB, ...} (32 rows), 256 threads x
// float4 covers exactly one 1024-float row per iteration.
//
//  - `row` is scalar (blockIdx-derived only) -> labels[row] is an s_load and
//    the centers row base lives in SGPRs; both dwordx4 loads use the
//    v_offset + s[base] form (minimal per-lane VALU).
//  - per-thread element sequence is BIT-IDENTICAL to the 352.8us baseline
//    (row b+2048n, k4 = tid), so numerics match (absmax 0.0).
//  - features is a read-once 256 MiB stream -> nontemporal loads; centers
//    (384 KB) stays hot in L2. unroll 4 -> 8 float4 in flight per thread.
//  - NO fusion, NO memset: R4 showed fill/memset dispatches in the captured
//    graph cost ~160 us fixed regardless of size; a 4-us finalize kernel is
//    strictly cheaper. R3 showed unroll2 + 64-VGPR cap regresses +17 us.
//
// clamp note: per-row distance is a sum of 1024 squares (magnitude ~2048);
// clip(d,1e-12,1e12) is a no-op on the true-label column. Masked-out entries
// clip to 1e-12 each -> constant (NCLS-1)*1e-12 added in the final kernel.
__global__ __launch_bounds__(NT) void center_loss_elem(
    const float* __restrict__ features,
    const float* __restrict__ centers,
    const int* __restrict__ labels,
    float* __restrict__ partials)
{
    const int tid = threadIdx.x;
    const vfloat4* __restrict__ f4 = (const vfloat4*)features;
    const float4*  __restrict__ c4 = (const float4*)centers;

    float acc = 0.f;
#pragma unroll 4
    for (int row = blockIdx.x; row < BATCH; row += NB) {
        const int lbl = labels[row];                        // block-uniform -> s_load
        const vfloat4 f = __builtin_nontemporal_load(&f4[(size_t)row * F4 + tid]);
        const float4 c = c4[(size_t)lbl * F4 + tid];
        const float dx = f.x - c.x, dy = f.y - c.y;
        const float dz = f.z - c.z, dw = f.w - c.w;
        acc += dx * dx + dy * dy + dz * dz + dw * dw;
    }

    // wave butterfly + tiny LDS block reduce (once per thread)
#pragma unroll
    for (int off = 32; off > 0; off >>= 1) acc += __shfl_xor(acc, off, 64);

    __shared__ float wave_sums[NT / 64];
    if ((tid & 63) == 0) wave_sums[tid >> 6] = acc;
    __syncthreads();
    if (tid == 0) {
        float s = 0.f;
#pragma unroll
        for (int w = 0; w < NT / 64; ++w) s += wave_sums[w];
        partials[blockIdx.x] = s;
    }
}

__global__ __launch_bounds__(256) void center_loss_final(
    const float* __restrict__ partials, float* __restrict__ out)
{
    __shared__ double sh[256];
    double s = 0.0;
    for (int i = threadIdx.x; i < NB; i += 256) s += (double)partials[i];
    sh[threadIdx.x] = s;
    __syncthreads();
    for (int stride = 128; stride > 0; stride >>= 1) {
        if (threadIdx.x < stride) sh[threadIdx.x] += sh[threadIdx.x + stride];
        __syncthreads();
    }
    if (threadIdx.x == 0) {
        const double masked = (double)(NCLS - 1) * 1e-12;  // clip of masked zeros
        out[0] = (float)(sh[0] / (double)BATCH + masked);
    }
}

extern "C" void kernel_launch(void* const* d_in, const int* in_sizes, int n_in,
                              void* d_out, int out_size, void* d_ws, size_t ws_size,
                              hipStream_t stream) {
    const float* features = (const float*)d_in[0];
    const float* centers  = (const float*)d_in[1];
    const int*   labels   = (const int*)d_in[2];
    float* out = (float*)d_out;
    float* partials = (float*)d_ws;   // 2048 floats = 8 KB scratch

    center_loss_elem<<<NB, NT, 0, stream>>>(features, centers, labels, partials);
    center_loss_final<<<1, 256, 0, stream>>>(partials, out);
}